// Round 9
// baseline (179.241 us; speedup 1.0000x reference)
//
#include <hip/hip_runtime.h>

typedef unsigned long long u64;
typedef unsigned int u32;

#define G 512
#define T 128
#define P 256
#define B 512

// ---------------- workspace layout ----------------
// pv_ws  : B*4 u64   = 16 KB  (packed param_vals, linear bit order)
// par_ws : G*16 u32  = 32 KB  (parity bits, [g][b>>5], bit = b&31)
#define PV_OFF    0
#define PAR_OFF   16384
#define WS_NEEDED (PAR_OFF + (size_t)G * 16 * 4)

// Linear bit order: bit k of word W <-> float (W*64 + k) of the flat array.
// Same permutation on matrices and param_vals -> AND-parity preserved.

__device__ __forceinline__ unsigned nzbit(unsigned u) {
    return (u | (0u - u)) >> 31;   // 1 iff u != 0
}

__device__ __forceinline__ u64 pack64(const uint4* sv) {
    uint4 f[16];
    #pragma unroll
    for (int i = 0; i < 16; ++i) f[i] = sv[i];
    __builtin_amdgcn_sched_barrier(0);
    unsigned lo = 0, hi = 0;
    #pragma unroll
    for (int i = 0; i < 8; ++i) {
        lo |= nzbit(f[i].x) << (4 * i + 0);
        lo |= nzbit(f[i].y) << (4 * i + 1);
        lo |= nzbit(f[i].z) << (4 * i + 2);
        lo |= nzbit(f[i].w) << (4 * i + 3);
    }
    #pragma unroll
    for (int i = 8; i < 16; ++i) {
        hi |= nzbit(f[i].x) << (4 * (i - 8) + 0);
        hi |= nzbit(f[i].y) << (4 * (i - 8) + 1);
        hi |= nzbit(f[i].z) << (4 * (i - 8) + 2);
        hi |= nzbit(f[i].w) << (4 * (i - 8) + 3);
    }
    return ((u64)hi << 32) | (u64)lo;
}

// ---------------- k1: pack pv + zero parity workspace (R5-verified) --------
__global__ __launch_bounds__(256) void pack_pv_zero_kernel(
    const float* __restrict__ pv, u64* __restrict__ pv_ws,
    uint4* __restrict__ par_zero)
{
    int tid = blockIdx.x * 256 + threadIdx.x;            // 0..2047
    pv_ws[tid] = pack64((const uint4*)(pv + (size_t)tid * 64));
    par_zero[tid] = make_uint4(0, 0, 0, 0);              // 2048*16B = 32 KB
}

// ---------------- k2: pipelined fused pack+compute ----------------
// One single-wave block per (graph g, quad of 4 term-groups): 4096 blocks.
// pv masks PRELOADED to registers (64 VGPRs) so the steady-state loop issues
// ZERO vmem ops besides the DMAs -> counted vmcnt is exact (in-order retire):
// queue = [pv(16)][DMA g0(8)][DMA g1(8)]; each vmcnt(8) == "previous buffer
// retired" while the freshly issued tile's 8 DMAs stay in flight across the
// whole convert+compute phase. Conversion/b-loop/atomicXor identical to
// R7-verified pi_group_kernel.
#define GRP 4
#define NGRP (T / GRP)                  // 32 groups per graph
#define NG 4                            // groups per wave
#define MAIN_BLOCKS (G * NGRP / NG)     // 4096

#define DMA_GROUP(gi, buf) do {                                               \
    const float* ps_ = psi_params + ((size_t)g * T + (size_t)(gi) * GRP) * P; \
    const float* qs_ = phi_params + ((size_t)g * T + (size_t)(gi) * GRP) * P; \
    _Pragma("unroll")                                                         \
    for (int k_ = 0; k_ < 4; ++k_)                                            \
        __builtin_amdgcn_global_load_lds(                                     \
            (const __attribute__((address_space(1))) u32*)(ps_ + k_ * 256 + lane * 4), \
            (__attribute__((address_space(3))) u32*)&stage[buf][k_ * 256],    \
            16, 0, 0);                                                        \
    _Pragma("unroll")                                                         \
    for (int k_ = 0; k_ < 4; ++k_)                                            \
        __builtin_amdgcn_global_load_lds(                                     \
            (const __attribute__((address_space(1))) u32*)(qs_ + k_ * 256 + lane * 4), \
            (__attribute__((address_space(3))) u32*)&stage[buf][1024 + k_ * 256], \
            16, 0, 0);                                                        \
} while (0)

#define CONVERT(buf) do {                                                     \
    _Pragma("unroll")                                                         \
    for (int t_ = 0; t_ < GRP; ++t_) {                                        \
        _Pragma("unroll")                                                     \
        for (int j_ = 0; j_ < 4; ++j_) {                                      \
            float xp_ = stage[buf][t_ * 256 + j_ * 64 + lane];                \
            ra[t_][j_]     = __ballot(xp_ != 0.0f);                           \
            float xq_ = stage[buf][1024 + t_ * 256 + j_ * 64 + lane];         \
            ra[t_][4 + j_] = __ballot(xq_ != 0.0f);                           \
        }                                                                     \
    }                                                                         \
} while (0)

// COMPUTE: registers only (pv in pva/pvb, masks in SGPRs) -> no vmem issued.
#define COMPUTE(gi) do {                                                      \
    unsigned pa_[GRP], qa_[GRP];                                              \
    _Pragma("unroll")                                                         \
    for (int t_ = 0; t_ < GRP; ++t_) {                                        \
        pa_[t_] = ((unsigned)psi_const[g * T + (gi) * GRP + t_]) & 1u;        \
        qa_[t_] = ((unsigned)phi_const[g * T + (gi) * GRP + t_]) & 1u;        \
    }                                                                         \
    _Pragma("unroll")                                                         \
    for (int c_ = 0; c_ < 8; ++c_) {                                          \
        u64 v0_ = pva[c_].x, v1_ = pva[c_].y;                                 \
        u64 v2_ = pvb[c_].x, v3_ = pvb[c_].y;                                 \
        unsigned e_ = 0;                                                      \
        _Pragma("unroll")                                                     \
        for (int t_ = 0; t_ < GRP; ++t_) {                                    \
            u64 m0_ = (ra[t_][0] & v0_) ^ (ra[t_][1] & v1_)                   \
                    ^ (ra[t_][2] & v2_) ^ (ra[t_][3] & v3_);                  \
            u64 m1_ = (ra[t_][4] & v0_) ^ (ra[t_][5] & v1_)                   \
                    ^ (ra[t_][6] & v2_) ^ (ra[t_][7] & v3_);                  \
            e_ ^= (((unsigned)__popcll(m0_) ^ pa_[t_])                        \
                 & ((unsigned)__popcll(m1_) ^ qa_[t_]));                      \
        }                                                                     \
        u64 bal_ = __ballot(e_ & 1u);                                         \
        if (lane == 2 * c_)     wacc ^= (unsigned)bal_;                       \
        if (lane == 2 * c_ + 1) wacc ^= (unsigned)(bal_ >> 32);               \
    }                                                                         \
} while (0)

__global__ __launch_bounds__(64) void pi_pipe_kernel(
    const int*   __restrict__ psi_const,
    const int*   __restrict__ phi_const,
    const float* __restrict__ psi_params,
    const float* __restrict__ phi_params,
    const u64*   __restrict__ pv_ws,
    unsigned*    __restrict__ par_ws)
{
    __shared__ __align__(16) float stage[2][GRP * 2 * 256];   // 2 x 8 KB

    const int lane = threadIdx.x;              // single wave
    const int g    = blockIdx.x >> 3;
    const int g0   = (blockIdx.x & 7) * NG;    // first of 4 group indices

    // ---- pv preload: 256 B/lane = 64 VGPRs; FIRST in the vmcnt queue ----
    ulonglong2 pva[8], pvb[8];
    #pragma unroll
    for (int c = 0; c < 8; ++c) {
        const ulonglong2* vp =
            (const ulonglong2*)(pv_ws + ((size_t)(c * 64) + lane) * 4);
        pva[c] = vp[0];
        pvb[c] = vp[1];
    }

    u64 ra[GRP][8];     // current group's masks (ballot results -> SGPRs)
    unsigned wacc = 0;

    // prologue: two tiles in flight
    DMA_GROUP(g0 + 0, 0);
    DMA_GROUP(g0 + 1, 1);

    // phase 0: vmcnt<=8 -> pv + DMA(g0+0) retired; DMA(g0+1) still in flight
    asm volatile("s_waitcnt vmcnt(8)" ::: "memory");
    __builtin_amdgcn_sched_barrier(0);
    CONVERT(0);
    asm volatile("s_waitcnt lgkmcnt(0)" ::: "memory");
    __builtin_amdgcn_sched_barrier(0);
    DMA_GROUP(g0 + 2, 0);
    COMPUTE(g0 + 0);

    // phase 1: vmcnt<=8 -> DMA(g0+1) retired; DMA(g0+2) in flight
    asm volatile("s_waitcnt vmcnt(8)" ::: "memory");
    __builtin_amdgcn_sched_barrier(0);
    CONVERT(1);
    asm volatile("s_waitcnt lgkmcnt(0)" ::: "memory");
    __builtin_amdgcn_sched_barrier(0);
    DMA_GROUP(g0 + 3, 1);
    COMPUTE(g0 + 1);

    // phase 2: vmcnt<=8 -> DMA(g0+2) retired; DMA(g0+3) in flight
    asm volatile("s_waitcnt vmcnt(8)" ::: "memory");
    __builtin_amdgcn_sched_barrier(0);
    CONVERT(0);
    COMPUTE(g0 + 2);

    // phase 3: drain
    asm volatile("s_waitcnt vmcnt(0)" ::: "memory");
    __builtin_amdgcn_sched_barrier(0);
    CONVERT(1);
    COMPUTE(g0 + 3);

    if (lane < 16) atomicXor(&par_ws[g * 16 + lane], wacc);
}

// ---------------- k3: epilogue (R5-verified), coalesced sign stores --------
__global__ __launch_bounds__(256) void epilogue_kernel(
    const unsigned* __restrict__ par_ws, float4* __restrict__ out)
{
    int id = blockIdx.x * 256 + threadIdx.x;     // 0..262143 = b*512 + g
    int b  = id >> 9;
    int gg = id & 511;
    unsigned w = par_ws[gg * 16 + (b >> 5)];
    float s = 1.0f - 2.0f * (float)((w >> (b & 31)) & 1u);
    out[id] = make_float4(s, 0.0f, 0.0f, 0.0f);
}

// ---------------- fallback path (round-0 verified kernels) ----------------
struct __align__(16) U64x2 { u64 x, y; };

__global__ __launch_bounds__(256) void pack_pv_kernel(
    const float* __restrict__ pv, u64* __restrict__ out)
{
    int lane = threadIdx.x & 63;
    int wave = threadIdx.x >> 6;
    int row  = blockIdx.x * 4 + wave;
    const float4* src = (const float4*)(pv + (size_t)row * P);
    float4 f = src[lane];
    u64 w0 = __ballot(f.x != 0.0f);
    u64 w1 = __ballot(f.y != 0.0f);
    u64 w2 = __ballot(f.z != 0.0f);
    u64 w3 = __ballot(f.w != 0.0f);
    if (lane == 0) {
        out[row * 4 + 0] = w0;
        out[row * 4 + 1] = w1;
        out[row * 4 + 2] = w2;
        out[row * 4 + 3] = w3;
    }
}

__global__ __launch_bounds__(512) void pi_main_kernel(
    const int*   __restrict__ psi_const,
    const float* __restrict__ psi_params,
    const int*   __restrict__ phi_const,
    const float* __restrict__ phi_params,
    const u64*   __restrict__ pv,
    float4*      __restrict__ out)
{
    __shared__ __align__(16) u64 rows[T * 8];
    __shared__ unsigned code_sm[T];

    const int g    = blockIdx.x;
    const int tid  = threadIdx.x;
    const int lane = tid & 63;
    const int wave = tid >> 6;

    if (tid < T) {
        unsigned pc = ((unsigned)psi_const[g * T + tid]) & 1u;
        unsigned qc = ((unsigned)phi_const[g * T + tid]) & 1u;
        code_sm[tid] = pc | (qc << 1);
    }

    for (int i = 0; i < 32; ++i) {
        int r = wave * 32 + i;
        int t = r & (T - 1);
        const float* mat = (r < T) ? psi_params : phi_params;
        int off = (r < T) ? 0 : 4;
        const float4* src = (const float4*)(mat + ((size_t)g * T + t) * P);
        float4 f = src[lane];
        u64 w0 = __ballot(f.x != 0.0f);
        u64 w1 = __ballot(f.y != 0.0f);
        u64 w2 = __ballot(f.z != 0.0f);
        u64 w3 = __ballot(f.w != 0.0f);
        if (lane == 0) {
            U64x2* d = (U64x2*)&rows[t * 8 + off];
            U64x2 a; a.x = w0; a.y = w1;
            U64x2 c; c.x = w2; c.y = w3;
            d[0] = a;
            d[1] = c;
        }
    }
    __syncthreads();

    const int b = tid;
    const u64* v = pv + (size_t)b * 4;
    u64 v0 = v[0], v1 = v[1], v2 = v[2], v3 = v[3];

    unsigned e = 0;
    #pragma unroll 8
    for (int t = 0; t < T; ++t) {
        const U64x2* row = (const U64x2*)&rows[t * 8];
        U64x2 p0 = row[0], p1 = row[1], q0 = row[2], q1 = row[3];
        u64 ma = (p0.x & v0) ^ (p0.y & v1) ^ (p1.x & v2) ^ (p1.y & v3);
        u64 mb = (q0.x & v0) ^ (q0.y & v1) ^ (q1.x & v2) ^ (q1.y & v3);
        unsigned c = code_sm[t];
        e ^= (((unsigned)__popcll(ma) ^ c) & ((unsigned)__popcll(mb) ^ (c >> 1)));
    }
    e &= 1u;

    float s = 1.0f - 2.0f * (float)e;
    out[(size_t)b * G + g] = make_float4(s, 0.0f, 0.0f, 0.0f);
}

// ---------------- launch ----------------
extern "C" void kernel_launch(void* const* d_in, const int* in_sizes, int n_in,
                              void* d_out, int out_size, void* d_ws, size_t ws_size,
                              hipStream_t stream) {
    const int*   psi_const  = (const int*)  d_in[0];
    const float* psi_params = (const float*)d_in[1];
    const int*   phi_const  = (const int*)  d_in[2];
    const float* phi_params = (const float*)d_in[3];
    const float* param_vals = (const float*)d_in[4];

    if (ws_size >= WS_NEEDED) {
        u64*      pv_ws  = (u64*)((char*)d_ws + PV_OFF);
        unsigned* par_ws = (unsigned*)((char*)d_ws + PAR_OFF);

        pack_pv_zero_kernel<<<8, 256, 0, stream>>>(
            param_vals, pv_ws, (uint4*)par_ws);
        pi_pipe_kernel<<<MAIN_BLOCKS, 64, 0, stream>>>(
            psi_const, phi_const, psi_params, phi_params, pv_ws, par_ws);
        epilogue_kernel<<<(B * G) / 256, 256, 0, stream>>>(
            par_ws, (float4*)d_out);
    } else {
        u64* pv_packed = (u64*)d_ws;
        pack_pv_kernel<<<B / 4, 256, 0, stream>>>(param_vals, pv_packed);
        pi_main_kernel<<<G, 512, 0, stream>>>(psi_const, psi_params,
                                              phi_const, phi_params,
                                              pv_packed, (float4*)d_out);
    }
}

// Round 10
// 173.035 us; speedup vs baseline: 1.0359x; 1.0359x over previous
//
#include <hip/hip_runtime.h>

typedef unsigned long long u64;
typedef unsigned int u32;

#define G 512
#define T 128
#define P 256
#define B 512

// ---------------- workspace layout ----------------
// pv_ws  : B*4 u64   = 16 KB  (packed param_vals, linear bit order)
// par_ws : G*16 u32  = 32 KB  (parity bits, [g][b>>5], bit = b&31)
#define PV_OFF    0
#define PAR_OFF   16384
#define WS_NEEDED (PAR_OFF + (size_t)G * 16 * 4)

// Linear bit order: bit k of word W <-> float (W*64 + k) of the flat array.
// Same permutation on matrices and param_vals -> AND-parity preserved.

__device__ __forceinline__ unsigned nzbit(unsigned u) {
    return (u | (0u - u)) >> 31;   // 1 iff u != 0
}

__device__ __forceinline__ u64 pack64(const uint4* sv) {
    uint4 f[16];
    #pragma unroll
    for (int i = 0; i < 16; ++i) f[i] = sv[i];
    __builtin_amdgcn_sched_barrier(0);
    unsigned lo = 0, hi = 0;
    #pragma unroll
    for (int i = 0; i < 8; ++i) {
        lo |= nzbit(f[i].x) << (4 * i + 0);
        lo |= nzbit(f[i].y) << (4 * i + 1);
        lo |= nzbit(f[i].z) << (4 * i + 2);
        lo |= nzbit(f[i].w) << (4 * i + 3);
    }
    #pragma unroll
    for (int i = 8; i < 16; ++i) {
        hi |= nzbit(f[i].x) << (4 * (i - 8) + 0);
        hi |= nzbit(f[i].y) << (4 * (i - 8) + 1);
        hi |= nzbit(f[i].z) << (4 * (i - 8) + 2);
        hi |= nzbit(f[i].w) << (4 * (i - 8) + 3);
    }
    return ((u64)hi << 32) | (u64)lo;
}

// ---------------- k1: pack pv + zero parity workspace (R5/R7-verified) -----
__global__ __launch_bounds__(256) void pack_pv_zero_kernel(
    const float* __restrict__ pv, u64* __restrict__ pv_ws,
    uint4* __restrict__ par_zero)
{
    int tid = blockIdx.x * 256 + threadIdx.x;            // 0..2047
    pv_ws[tid] = pack64((const uint4*)(pv + (size_t)tid * 64));
    par_zero[tid] = make_uint4(0, 0, 0, 0);              // 2048*16B = 32 KB
}

// ---------------- k2: fused pack+compute, 4 independent waves/block --------
// Wave = (graph g, 4-term group) — EXACTLY the R7-verified pi_group_kernel
// body, but 4 such waves share one 256-thread block (own 8 KB stage slice,
// no __syncthreads): 4096 blocks instead of 16384 single-wave workgroups.
// 32 KB LDS/block -> 5 blocks/CU = 20 waves/CU (was ~14): more statistical
// DMA/compute overlap across waves, 4x fewer workgroup launches.
#define GRP 4
#define NGRP (T / GRP)                  // 32 groups per graph
#define MAIN_BLOCKS (G * NGRP / 4)      // 4096 blocks x 4 waves

__global__ __launch_bounds__(256) void pi_group4_kernel(
    const int*   __restrict__ psi_const,
    const int*   __restrict__ phi_const,
    const float* __restrict__ psi_params,
    const float* __restrict__ phi_params,
    const u64*   __restrict__ pv_ws,
    unsigned*    __restrict__ par_ws)
{
    __shared__ __align__(16) float stage[4][2 * GRP * 256];   // 4 x 8 KB

    const int lane = threadIdx.x & 63;
    const int wv   = threadIdx.x >> 6;
    const int g    = blockIdx.x >> 3;                  // 8 blocks per graph
    const int grp  = (blockIdx.x & 7) * 4 + wv;        // this wave's group

    const float* ps = psi_params + ((size_t)g * T + grp * GRP) * P;
    const float* qs = phi_params + ((size_t)g * T + grp * GRP) * P;

    // ---- DMA 8 KB into this wave's slice: linear dest + linear src ----
    #pragma unroll
    for (int k = 0; k < 4; ++k) {
        __builtin_amdgcn_global_load_lds(
            (const __attribute__((address_space(1))) u32*)(ps + k * 256 + lane * 4),
            (__attribute__((address_space(3))) u32*)&stage[wv][k * 256],
            16, 0, 0);
    }
    #pragma unroll
    for (int k = 0; k < 4; ++k) {
        __builtin_amdgcn_global_load_lds(
            (const __attribute__((address_space(1))) u32*)(qs + k * 256 + lane * 4),
            (__attribute__((address_space(3))) u32*)&stage[wv][1024 + k * 256],
            16, 0, 0);
    }
    asm volatile("s_waitcnt vmcnt(0)" ::: "memory");   // per-wave; no barrier

    // ---- convert: 32 ballots -> 32 wave-uniform packed u64 ----
    u64 ra[GRP][8];    // [t][0..3]=psi words, [4..7]=phi words
    #pragma unroll
    for (int t = 0; t < GRP; ++t) {
        #pragma unroll
        for (int j = 0; j < 4; ++j) {
            float xp = stage[wv][t * 256 + j * 64 + lane];        // stride-1
            ra[t][j]     = __ballot(xp != 0.0f);
            float xq = stage[wv][1024 + t * 256 + j * 64 + lane];
            ra[t][4 + j] = __ballot(xq != 0.0f);
        }
    }

    unsigned pa[GRP], qa[GRP];
    #pragma unroll
    for (int t = 0; t < GRP; ++t) {
        pa[t] = ((unsigned)psi_const[g * T + grp * GRP + t]) & 1u;
        qa[t] = ((unsigned)phi_const[g * T + grp * GRP + t]) & 1u;
    }

    // ---- b-loop: 8 chunks of 64 b, lane = b within chunk ----
    unsigned wacc = 0;
    #pragma unroll
    for (int c = 0; c < 8; ++c) {
        const ulonglong2* vp =
            (const ulonglong2*)(pv_ws + ((size_t)(c * 64) + lane) * 4);
        ulonglong2 ua = vp[0], ub = vp[1];
        u64 v0 = ua.x, v1 = ua.y, v2 = ub.x, v3 = ub.y;

        unsigned e = 0;
        #pragma unroll
        for (int t = 0; t < GRP; ++t) {
            u64 m0 = (ra[t][0] & v0) ^ (ra[t][1] & v1)
                   ^ (ra[t][2] & v2) ^ (ra[t][3] & v3);
            u64 m1 = (ra[t][4] & v0) ^ (ra[t][5] & v1)
                   ^ (ra[t][6] & v2) ^ (ra[t][7] & v3);
            e ^= (((unsigned)__popcll(m0) ^ pa[t])
                & ((unsigned)__popcll(m1) ^ qa[t]));
        }

        u64 bal = __ballot(e & 1u);     // bit l = parity of b = c*64 + l
        if (lane == 2 * c)     wacc = (unsigned)bal;
        if (lane == 2 * c + 1) wacc = (unsigned)(bal >> 32);
    }

    if (lane < 16) atomicXor(&par_ws[g * 16 + lane], wacc);
}

// ---------------- k3: epilogue (R5/R7-verified), coalesced stores ----------
__global__ __launch_bounds__(256) void epilogue_kernel(
    const unsigned* __restrict__ par_ws, float4* __restrict__ out)
{
    int id = blockIdx.x * 256 + threadIdx.x;     // 0..262143 = b*512 + g
    int b  = id >> 9;
    int gg = id & 511;
    unsigned w = par_ws[gg * 16 + (b >> 5)];
    float s = 1.0f - 2.0f * (float)((w >> (b & 31)) & 1u);
    out[id] = make_float4(s, 0.0f, 0.0f, 0.0f);
}

// ---------------- fallback path (round-0 verified kernels) ----------------
struct __align__(16) U64x2 { u64 x, y; };

__global__ __launch_bounds__(256) void pack_pv_kernel(
    const float* __restrict__ pv, u64* __restrict__ out)
{
    int lane = threadIdx.x & 63;
    int wave = threadIdx.x >> 6;
    int row  = blockIdx.x * 4 + wave;
    const float4* src = (const float4*)(pv + (size_t)row * P);
    float4 f = src[lane];
    u64 w0 = __ballot(f.x != 0.0f);
    u64 w1 = __ballot(f.y != 0.0f);
    u64 w2 = __ballot(f.z != 0.0f);
    u64 w3 = __ballot(f.w != 0.0f);
    if (lane == 0) {
        out[row * 4 + 0] = w0;
        out[row * 4 + 1] = w1;
        out[row * 4 + 2] = w2;
        out[row * 4 + 3] = w3;
    }
}

__global__ __launch_bounds__(512) void pi_main_kernel(
    const int*   __restrict__ psi_const,
    const float* __restrict__ psi_params,
    const int*   __restrict__ phi_const,
    const float* __restrict__ phi_params,
    const u64*   __restrict__ pv,
    float4*      __restrict__ out)
{
    __shared__ __align__(16) u64 rows[T * 8];
    __shared__ unsigned code_sm[T];

    const int g    = blockIdx.x;
    const int tid  = threadIdx.x;
    const int lane = tid & 63;
    const int wave = tid >> 6;

    if (tid < T) {
        unsigned pc = ((unsigned)psi_const[g * T + tid]) & 1u;
        unsigned qc = ((unsigned)phi_const[g * T + tid]) & 1u;
        code_sm[tid] = pc | (qc << 1);
    }

    for (int i = 0; i < 32; ++i) {
        int r = wave * 32 + i;
        int t = r & (T - 1);
        const float* mat = (r < T) ? psi_params : phi_params;
        int off = (r < T) ? 0 : 4;
        const float4* src = (const float4*)(mat + ((size_t)g * T + t) * P);
        float4 f = src[lane];
        u64 w0 = __ballot(f.x != 0.0f);
        u64 w1 = __ballot(f.y != 0.0f);
        u64 w2 = __ballot(f.z != 0.0f);
        u64 w3 = __ballot(f.w != 0.0f);
        if (lane == 0) {
            U64x2* d = (U64x2*)&rows[t * 8 + off];
            U64x2 a; a.x = w0; a.y = w1;
            U64x2 c; c.x = w2; c.y = w3;
            d[0] = a;
            d[1] = c;
        }
    }
    __syncthreads();

    const int b = tid;
    const u64* v = pv + (size_t)b * 4;
    u64 v0 = v[0], v1 = v[1], v2 = v[2], v3 = v[3];

    unsigned e = 0;
    #pragma unroll 8
    for (int t = 0; t < T; ++t) {
        const U64x2* row = (const U64x2*)&rows[t * 8];
        U64x2 p0 = row[0], p1 = row[1], q0 = row[2], q1 = row[3];
        u64 ma = (p0.x & v0) ^ (p0.y & v1) ^ (p1.x & v2) ^ (p1.y & v3);
        u64 mb = (q0.x & v0) ^ (q0.y & v1) ^ (q1.x & v2) ^ (q1.y & v3);
        unsigned c = code_sm[t];
        e ^= (((unsigned)__popcll(ma) ^ c) & ((unsigned)__popcll(mb) ^ (c >> 1)));
    }
    e &= 1u;

    float s = 1.0f - 2.0f * (float)e;
    out[(size_t)b * G + g] = make_float4(s, 0.0f, 0.0f, 0.0f);
}

// ---------------- launch ----------------
extern "C" void kernel_launch(void* const* d_in, const int* in_sizes, int n_in,
                              void* d_out, int out_size, void* d_ws, size_t ws_size,
                              hipStream_t stream) {
    const int*   psi_const  = (const int*)  d_in[0];
    const float* psi_params = (const float*)d_in[1];
    const int*   phi_const  = (const int*)  d_in[2];
    const float* phi_params = (const float*)d_in[3];
    const float* param_vals = (const float*)d_in[4];

    if (ws_size >= WS_NEEDED) {
        u64*      pv_ws  = (u64*)((char*)d_ws + PV_OFF);
        unsigned* par_ws = (unsigned*)((char*)d_ws + PAR_OFF);

        pack_pv_zero_kernel<<<8, 256, 0, stream>>>(
            param_vals, pv_ws, (uint4*)par_ws);
        pi_group4_kernel<<<MAIN_BLOCKS, 256, 0, stream>>>(
            psi_const, phi_const, psi_params, phi_params, pv_ws, par_ws);
        epilogue_kernel<<<(B * G) / 256, 256, 0, stream>>>(
            par_ws, (float4*)d_out);
    } else {
        u64* pv_packed = (u64*)d_ws;
        pack_pv_kernel<<<B / 4, 256, 0, stream>>>(param_vals, pv_packed);
        pi_main_kernel<<<G, 512, 0, stream>>>(psi_const, psi_params,
                                              phi_const, phi_params,
                                              pv_packed, (float4*)d_out);
    }
}

// Round 11
// 169.718 us; speedup vs baseline: 1.0561x; 1.0195x over previous
//
#include <hip/hip_runtime.h>

typedef unsigned long long u64;
typedef unsigned int u32;

#define G 512
#define T 128
#define P 256
#define B 512

// ---------------- workspace layout ----------------
// pv_ws  : B*4 u64   = 16 KB  (packed param_vals, linear bit order)
// par_ws : G*16 u32  = 32 KB  (parity bits, [g][b>>5], bit = b&31)
#define PV_OFF    0
#define PAR_OFF   16384
#define WS_NEEDED (PAR_OFF + (size_t)G * 16 * 4)

// Linear bit order: bit k of word W <-> float (W*64 + k) of the flat array.
// Same permutation on matrices and param_vals -> AND-parity preserved.

__device__ __forceinline__ unsigned nzbit(unsigned u) {
    return (u | (0u - u)) >> 31;   // 1 iff u != 0
}

__device__ __forceinline__ u64 pack64(const uint4* sv) {
    uint4 f[16];
    #pragma unroll
    for (int i = 0; i < 16; ++i) f[i] = sv[i];
    __builtin_amdgcn_sched_barrier(0);
    unsigned lo = 0, hi = 0;
    #pragma unroll
    for (int i = 0; i < 8; ++i) {
        lo |= nzbit(f[i].x) << (4 * i + 0);
        lo |= nzbit(f[i].y) << (4 * i + 1);
        lo |= nzbit(f[i].z) << (4 * i + 2);
        lo |= nzbit(f[i].w) << (4 * i + 3);
    }
    #pragma unroll
    for (int i = 8; i < 16; ++i) {
        hi |= nzbit(f[i].x) << (4 * (i - 8) + 0);
        hi |= nzbit(f[i].y) << (4 * (i - 8) + 1);
        hi |= nzbit(f[i].z) << (4 * (i - 8) + 2);
        hi |= nzbit(f[i].w) << (4 * (i - 8) + 3);
    }
    return ((u64)hi << 32) | (u64)lo;
}

// ---------------- k1: pack pv + zero parity workspace (R5/R7-verified) -----
__global__ __launch_bounds__(256) void pack_pv_zero_kernel(
    const float* __restrict__ pv, u64* __restrict__ pv_ws,
    uint4* __restrict__ par_zero)
{
    int tid = blockIdx.x * 256 + threadIdx.x;            // 0..2047
    pv_ws[tid] = pack64((const uint4*)(pv + (size_t)tid * 64));
    par_zero[tid] = make_uint4(0, 0, 0, 0);              // 2048*16B = 32 KB
}

// ---------------- k2: fused pack+compute, max-occupancy variant ------------
// Wave = (graph g, 2-term group); 4 independent waves per 256-thread block
// (own 4 KB stage slice, no __syncthreads). 16 KB LDS/block -> the WAVE-SLOT
// limit binds: 8 blocks/CU x 4 waves = 32 waves/CU (hw max), ~3x R10's
// measured residency -> denser statistical DMA/compute overlap.
// Conversion ballots, b-loop math, ballot-packing, atomicXor decomposition
// bit-identical to R7/R10-verified code; only GRP and geometry changed.
#define GRP 2
#define NGRP (T / GRP)                  // 64 groups per graph
#define MAIN_BLOCKS (G * NGRP / 4)      // 8192 blocks x 4 waves

__global__ __launch_bounds__(256) void pi_group2_kernel(
    const int*   __restrict__ psi_const,
    const int*   __restrict__ phi_const,
    const float* __restrict__ psi_params,
    const float* __restrict__ phi_params,
    const u64*   __restrict__ pv_ws,
    unsigned*    __restrict__ par_ws)
{
    __shared__ __align__(16) float stage[4][2 * GRP * 256];   // 4 x 4 KB

    const int lane = threadIdx.x & 63;
    const int wv   = threadIdx.x >> 6;
    const int g    = blockIdx.x >> 4;                  // 16 blocks per graph
    const int grp  = (blockIdx.x & 15) * 4 + wv;       // group in [0,64)

    const float* ps = psi_params + ((size_t)g * T + grp * GRP) * P;
    const float* qs = phi_params + ((size_t)g * T + grp * GRP) * P;

    // ---- DMA 4 KB into this wave's slice: linear dest + linear src ----
    #pragma unroll
    for (int k = 0; k < GRP; ++k) {
        __builtin_amdgcn_global_load_lds(
            (const __attribute__((address_space(1))) u32*)(ps + k * 256 + lane * 4),
            (__attribute__((address_space(3))) u32*)&stage[wv][k * 256],
            16, 0, 0);
    }
    #pragma unroll
    for (int k = 0; k < GRP; ++k) {
        __builtin_amdgcn_global_load_lds(
            (const __attribute__((address_space(1))) u32*)(qs + k * 256 + lane * 4),
            (__attribute__((address_space(3))) u32*)&stage[wv][GRP * 256 + k * 256],
            16, 0, 0);
    }
    asm volatile("s_waitcnt vmcnt(0)" ::: "memory");   // per-wave; no barrier

    // ---- convert: 16 ballots -> 16 wave-uniform packed u64 ----
    u64 ra[GRP][8];    // [t][0..3]=psi words, [4..7]=phi words
    #pragma unroll
    for (int t = 0; t < GRP; ++t) {
        #pragma unroll
        for (int j = 0; j < 4; ++j) {
            float xp = stage[wv][t * 256 + j * 64 + lane];              // stride-1
            ra[t][j]     = __ballot(xp != 0.0f);
            float xq = stage[wv][GRP * 256 + t * 256 + j * 64 + lane];
            ra[t][4 + j] = __ballot(xq != 0.0f);
        }
    }

    unsigned pa[GRP], qa[GRP];
    #pragma unroll
    for (int t = 0; t < GRP; ++t) {
        pa[t] = ((unsigned)psi_const[g * T + grp * GRP + t]) & 1u;
        qa[t] = ((unsigned)phi_const[g * T + grp * GRP + t]) & 1u;
    }

    // ---- b-loop: 8 chunks of 64 b, lane = b within chunk ----
    unsigned wacc = 0;
    #pragma unroll
    for (int c = 0; c < 8; ++c) {
        const ulonglong2* vp =
            (const ulonglong2*)(pv_ws + ((size_t)(c * 64) + lane) * 4);
        ulonglong2 ua = vp[0], ub = vp[1];
        u64 v0 = ua.x, v1 = ua.y, v2 = ub.x, v3 = ub.y;

        unsigned e = 0;
        #pragma unroll
        for (int t = 0; t < GRP; ++t) {
            u64 m0 = (ra[t][0] & v0) ^ (ra[t][1] & v1)
                   ^ (ra[t][2] & v2) ^ (ra[t][3] & v3);
            u64 m1 = (ra[t][4] & v0) ^ (ra[t][5] & v1)
                   ^ (ra[t][6] & v2) ^ (ra[t][7] & v3);
            e ^= (((unsigned)__popcll(m0) ^ pa[t])
                & ((unsigned)__popcll(m1) ^ qa[t]));
        }

        u64 bal = __ballot(e & 1u);     // bit l = parity of b = c*64 + l
        if (lane == 2 * c)     wacc = (unsigned)bal;
        if (lane == 2 * c + 1) wacc = (unsigned)(bal >> 32);
    }

    if (lane < 16) atomicXor(&par_ws[g * 16 + lane], wacc);
}

// ---------------- k3: epilogue (R5/R7-verified), coalesced stores ----------
__global__ __launch_bounds__(256) void epilogue_kernel(
    const unsigned* __restrict__ par_ws, float4* __restrict__ out)
{
    int id = blockIdx.x * 256 + threadIdx.x;     // 0..262143 = b*512 + g
    int b  = id >> 9;
    int gg = id & 511;
    unsigned w = par_ws[gg * 16 + (b >> 5)];
    float s = 1.0f - 2.0f * (float)((w >> (b & 31)) & 1u);
    out[id] = make_float4(s, 0.0f, 0.0f, 0.0f);
}

// ---------------- fallback path (round-0 verified kernels) ----------------
struct __align__(16) U64x2 { u64 x, y; };

__global__ __launch_bounds__(256) void pack_pv_kernel(
    const float* __restrict__ pv, u64* __restrict__ out)
{
    int lane = threadIdx.x & 63;
    int wave = threadIdx.x >> 6;
    int row  = blockIdx.x * 4 + wave;
    const float4* src = (const float4*)(pv + (size_t)row * P);
    float4 f = src[lane];
    u64 w0 = __ballot(f.x != 0.0f);
    u64 w1 = __ballot(f.y != 0.0f);
    u64 w2 = __ballot(f.z != 0.0f);
    u64 w3 = __ballot(f.w != 0.0f);
    if (lane == 0) {
        out[row * 4 + 0] = w0;
        out[row * 4 + 1] = w1;
        out[row * 4 + 2] = w2;
        out[row * 4 + 3] = w3;
    }
}

__global__ __launch_bounds__(512) void pi_main_kernel(
    const int*   __restrict__ psi_const,
    const float* __restrict__ psi_params,
    const int*   __restrict__ phi_const,
    const float* __restrict__ phi_params,
    const u64*   __restrict__ pv,
    float4*      __restrict__ out)
{
    __shared__ __align__(16) u64 rows[T * 8];
    __shared__ unsigned code_sm[T];

    const int g    = blockIdx.x;
    const int tid  = threadIdx.x;
    const int lane = tid & 63;
    const int wave = tid >> 6;

    if (tid < T) {
        unsigned pc = ((unsigned)psi_const[g * T + tid]) & 1u;
        unsigned qc = ((unsigned)phi_const[g * T + tid]) & 1u;
        code_sm[tid] = pc | (qc << 1);
    }

    for (int i = 0; i < 32; ++i) {
        int r = wave * 32 + i;
        int t = r & (T - 1);
        const float* mat = (r < T) ? psi_params : phi_params;
        int off = (r < T) ? 0 : 4;
        const float4* src = (const float4*)(mat + ((size_t)g * T + t) * P);
        float4 f = src[lane];
        u64 w0 = __ballot(f.x != 0.0f);
        u64 w1 = __ballot(f.y != 0.0f);
        u64 w2 = __ballot(f.z != 0.0f);
        u64 w3 = __ballot(f.w != 0.0f);
        if (lane == 0) {
            U64x2* d = (U64x2*)&rows[t * 8 + off];
            U64x2 a; a.x = w0; a.y = w1;
            U64x2 c; c.x = w2; c.y = w3;
            d[0] = a;
            d[1] = c;
        }
    }
    __syncthreads();

    const int b = tid;
    const u64* v = pv + (size_t)b * 4;
    u64 v0 = v[0], v1 = v[1], v2 = v[2], v3 = v[3];

    unsigned e = 0;
    #pragma unroll 8
    for (int t = 0; t < T; ++t) {
        const U64x2* row = (const U64x2*)&rows[t * 8];
        U64x2 p0 = row[0], p1 = row[1], q0 = row[2], q1 = row[3];
        u64 ma = (p0.x & v0) ^ (p0.y & v1) ^ (p1.x & v2) ^ (p1.y & v3);
        u64 mb = (q0.x & v0) ^ (q0.y & v1) ^ (q1.x & v2) ^ (q1.y & v3);
        unsigned c = code_sm[t];
        e ^= (((unsigned)__popcll(ma) ^ c) & ((unsigned)__popcll(mb) ^ (c >> 1)));
    }
    e &= 1u;

    float s = 1.0f - 2.0f * (float)e;
    out[(size_t)b * G + g] = make_float4(s, 0.0f, 0.0f, 0.0f);
}

// ---------------- launch ----------------
extern "C" void kernel_launch(void* const* d_in, const int* in_sizes, int n_in,
                              void* d_out, int out_size, void* d_ws, size_t ws_size,
                              hipStream_t stream) {
    const int*   psi_const  = (const int*)  d_in[0];
    const float* psi_params = (const float*)d_in[1];
    const int*   phi_const  = (const int*)  d_in[2];
    const float* phi_params = (const float*)d_in[3];
    const float* param_vals = (const float*)d_in[4];

    if (ws_size >= WS_NEEDED) {
        u64*      pv_ws  = (u64*)((char*)d_ws + PV_OFF);
        unsigned* par_ws = (unsigned*)((char*)d_ws + PAR_OFF);

        pack_pv_zero_kernel<<<8, 256, 0, stream>>>(
            param_vals, pv_ws, (uint4*)par_ws);
        pi_group2_kernel<<<MAIN_BLOCKS, 256, 0, stream>>>(
            psi_const, phi_const, psi_params, phi_params, pv_ws, par_ws);
        epilogue_kernel<<<(B * G) / 256, 256, 0, stream>>>(
            par_ws, (float4*)d_out);
    } else {
        u64* pv_packed = (u64*)d_ws;
        pack_pv_kernel<<<B / 4, 256, 0, stream>>>(param_vals, pv_packed);
        pi_main_kernel<<<G, 512, 0, stream>>>(psi_const, psi_params,
                                              phi_const, phi_params,
                                              pv_packed, (float4*)d_out);
    }
}